// Round 3
// baseline (478.464 us; speedup 1.0000x reference)
//
#include <hip/hip_runtime.h>
#include <math.h>

// Workspace layout (4-byte words):
#define W2OFF  0        // 8192 floats: W2[e][d] = sum_o key[e][o]*Wq[o][d]
#define B2OFF  8192     // 8 floats:    b2[e]    = sum_d bq[d]*key[e][d]
#define SCOFF  8200     // 512 floats:  score sums [batch][e]
#define AUXOFF 8712     // 1 float:     sum of w*log(w+1e-9)
#define CNTOFF 8713     // 64 ints:     per-batch block-arrival counters
#define GDOFF  8777     // 1 int:       batch-finisher arrival counter
#define ZTOT   578      // words to zero starting at SCOFF (512+1+64+1)
#define KEYP   1088     // skew-padded per-expert LDS stride for key

// ---------------- k01: W2 = key@Wq, b2 = bq.key, zero accumulators ----------------
__global__ __launch_bounds__(256) void k01_prep(const float* __restrict__ Wq,
                                                const float* __restrict__ key,
                                                const float* __restrict__ bq,
                                                float* __restrict__ ws) {
    __shared__ __attribute__((aligned(16))) float keyl[8 * KEYP];  // 34 KB
    __shared__ float part[256 * 8];                                // 8 KB
    __shared__ float part2[64];
    int tid = threadIdx.x;
    int blk = blockIdx.x;

    // distributed zeroing: 128 blocks x 5 words covers 578
    if (tid < 5) {
        int i = blk * 5 + tid;
        if (i < ZTOT) ws[SCOFF + i] = 0.0f;
    }

    // stage key with skew (scalar stores; global reads stay coalesced)
    #pragma unroll
    for (int k = 0; k < 32; ++k) {
        int idx = tid + 256 * k;         // 0..8191
        int e = idx >> 10, o = idx & 1023;
        keyl[e * KEYP + o + (o >> 5)] = key[idx];
    }
    __syncthreads();

    int dl = tid & 7;
    int og = tid >> 3;                   // 0..31
    int d  = blk * 8 + dl;
    int kob = og * 33;                   // og*32 + skew(og)
    float acc[8];
    #pragma unroll
    for (int e = 0; e < 8; ++e) acc[e] = 0.0f;
    #pragma unroll
    for (int oo = 0; oo < 32; ++oo) {    // full unroll: 32 Wq loads in flight
        int o = og * 32 + oo;
        float wv = Wq[o * 1024 + d];
        #pragma unroll
        for (int e = 0; e < 8; ++e) acc[e] += keyl[e * KEYP + kob + oo] * wv;
    }
    #pragma unroll
    for (int e = 0; e < 8; ++e) part[tid * 8 + e] = acc[e];
    __syncthreads();
    if (tid < 64) {
        int d2 = tid >> 3, e = tid & 7;
        float s = 0.0f;
        #pragma unroll
        for (int g = 0; g < 32; ++g) s += part[(g * 8 + d2) * 8 + e];
        ws[W2OFF + e * 1024 + blk * 8 + d2] = s;
    }

    // block 0 additionally computes b2 using the LDS-staged key (tree reduce)
    if (blk == 0) {
        __syncthreads();
        float p[8];
        #pragma unroll
        for (int e = 0; e < 8; ++e) p[e] = 0.0f;
        #pragma unroll
        for (int k = 0; k < 4; ++k) {
            int d2 = tid + 256 * k;
            float bv = bq[d2];
            int kd = d2 + (d2 >> 5);
            #pragma unroll
            for (int e = 0; e < 8; ++e) p[e] += bv * keyl[e * KEYP + kd];
        }
        #pragma unroll
        for (int e = 0; e < 8; ++e) part[tid * 8 + e] = p[e];
        __syncthreads();
        if (tid < 64) {
            int e = tid & 7, g = tid >> 3;
            float s = 0.0f;
            #pragma unroll
            for (int k = 0; k < 32; ++k) s += part[(g * 32 + k) * 8 + e];
            part2[g * 8 + e] = s;
        }
        __syncthreads();
        if (tid < 8) {
            float s = 0.0f;
            #pragma unroll
            for (int g = 0; g < 8; ++g) s += part2[g * 8 + tid];
            ws[B2OFF + tid] = s;
        }
    }
}

__device__ __forceinline__ void top2_of8(const float* v, int& i1, int& i2) {
    i1 = 0; float b1 = v[0];
    #pragma unroll
    for (int e = 1; e < 8; ++e) if (v[e] > b1) { b1 = v[e]; i1 = e; }
    i2 = -1; float b2 = -3.4e38f;
    #pragma unroll
    for (int e = 0; e < 8; ++e) if (e != i1 && v[e] > b2) { b2 = v[e]; i2 = e; }
}

// ---------------- k2: stream x -> scores -> INLINE softmax -> fused finisher ----------------
// 1024 blocks x 256 thr; block = 64 consecutive tokens of one batch.
// LDS = 32KB (W2) + 8KB (transpose, finisher scratch aliased in) = 40960 B
// exactly -> 4 blocks/CU (was 3 at 43520). Softmax is fully inline: after the
// r-group shuffle reduce every lane holds the complete raw dot for
// (token, e=lane>>3) replicated over r; masks 8/16/32 reduce across experts.
// No phase-B serial tail, no sraw buffer, transcendentals hidden under the
// memory stream. Cross-block comms are atomics-only (NO threadfence: r1
// showed the XCD-L2 invalidate costs 5x).
__global__ __launch_bounds__(256, 4) void k2_main(const float* __restrict__ x,
                                                  float* __restrict__ ws,
                                                  float* __restrict__ out) {
    __shared__ __attribute__((aligned(16))) float w2l[8 * 1024];    // 32 KB
    __shared__ __attribute__((aligned(16))) float part[4 * 64 * 8]; // 8 KB per-wave [8][64]

    int tid  = threadIdx.x;
    int blk  = blockIdx.x;
    int lane = tid & 63;
    int w    = tid >> 6;
    int batch = blk >> 4;
    int tb    = blk * 64;
    int e = lane >> 3;      // expert owned after transpose
    int r = lane & 7;       // reduction slice -> cheap shfl masks 1/2/4

    float4* wl4 = (float4*)w2l;
    const float4* wg4 = (const float4*)(ws + W2OFF);
    #pragma unroll
    for (int k = 0; k < 8; ++k) wl4[tid + 256 * k] = wg4[tid + 256 * k];

    float b2e = ws[B2OFF + e];           // per-lane bias for owned expert
    const float scale = 0.03125f;        // 1024^-0.5
    float ssum = 0.0f;                   // score-sum accumulator (expert e, this wave's tokens)
    float aux  = 0.0f;                   // aux accumulator (expert e, this wave's tokens)
    __syncthreads();

    const float4* x4 = (const float4*)x;
    float* pw = part + w * 512;

    for (int p = 0; p < 4; ++p) {
        int t0 = tb + w * 16 + p * 4;
        float acc[4][8];
        #pragma unroll
        for (int j = 0; j < 4; ++j)
            #pragma unroll
            for (int c = 0; c < 8; ++c) acc[j][c] = 0.0f;

        #pragma unroll
        for (int i = 0; i < 4; ++i) {
            float4 xr[4];
            #pragma unroll
            for (int j = 0; j < 4; ++j)
                xr[j] = x4[(size_t)(t0 + j) * 256 + i * 64 + lane];
            #pragma unroll
            for (int c = 0; c < 8; ++c) {
                float4 w4 = wl4[c * 256 + i * 64 + lane];
                #pragma unroll
                for (int j = 0; j < 4; ++j)
                    acc[j][c] += w4.x * xr[j].x + w4.y * xr[j].y +
                                 w4.z * xr[j].z + w4.w * xr[j].w;
            }
        }

        #pragma unroll
        for (int j = 0; j < 4; ++j) {
            // swizzled wave-internal transpose: <=2-way bank alias on write & read
            #pragma unroll
            for (int c = 0; c < 8; ++c)
                pw[c * 64 + (lane ^ (c << 3))] = acc[j][c];
            float s = 0.0f;
            #pragma unroll
            for (int m = 0; m < 8; ++m)
                s += pw[e * 64 + ((r + 8 * m) ^ (e << 3))];
            s += __shfl_xor(s, 1);
            s += __shfl_xor(s, 2);
            s += __shfl_xor(s, 4);
            // s = full raw dot (token t0+j, expert e), replicated over r.
            float sc = (s + b2e) * scale;
            float mx = sc;
            mx = fmaxf(mx, __shfl_xor(mx, 8));
            mx = fmaxf(mx, __shfl_xor(mx, 16));
            mx = fmaxf(mx, __shfl_xor(mx, 32));
            float wv = expf(sc - mx);
            float sm = wv;
            sm += __shfl_xor(sm, 8);
            sm += __shfl_xor(sm, 16);
            sm += __shfl_xor(sm, 32);
            float wgt = wv / sm;
            ssum += wgt;
            aux  += wgt * logf(wgt + 1e-9f);
        }
    }

    // cross-expert reduce of aux (lane value covers expert e only; replicated over r)
    aux += __shfl_xor(aux, 8);
    aux += __shfl_xor(aux, 16);
    aux += __shfl_xor(aux, 32);

    __syncthreads();                      // transpose buffer free; reuse for block reduce
    if (r == 0) part[w * 8 + e] = ssum;   // 32 floats
    if (lane == 0) part[32 + w] = aux;    // 4 floats
    __syncthreads();
    if (tid < 8) {
        float s2 = part[tid] + part[8 + tid] + part[16 + tid] + part[24 + tid];
        atomicAdd(&ws[SCOFF + batch * 8 + tid], s2);
    }
    if (tid == 0) {
        float a = part[32] + part[33] + part[34] + part[35];
        atomicAdd(&ws[AUXOFF], a);
    }

    // ---- fused finisher; atomics-only, NO threadfence ----
    int* wsi = (int*)ws;
    float* sc8  = part + 40;              // aliases into part (free now)
    int*   cnt8 = (int*)(part + 48);
    int*   sfp  = (int*)(part + 56);
    __syncthreads();   // compiler emits s_waitcnt vmcnt(0): score/aux atomics complete
    if (tid == 0) {
        asm volatile("s_waitcnt vmcnt(0)" ::: "memory");
        int prev = atomicAdd(&wsi[CNTOFF + batch], 1);
        *sfp = (prev == 15) ? 1 : 0;
    }
    __syncthreads();
    if (*sfp) {
        // coherent read of this batch's final score sums via atomic RMW
        if (tid < 8) sc8[tid] = atomicAdd(&ws[SCOFF + batch * 8 + tid], 0.0f);
        __syncthreads();
        float v[8];
        #pragma unroll
        for (int c = 0; c < 8; ++c) v[c] = sc8[c];
        int i1, i2;
        top2_of8(v, i1, i2);
        float m[8];
        #pragma unroll
        for (int c = 0; c < 8; ++c) m[c] = (c == i1 || c == i2) ? 1.0f : 0.0f;
        float4 mA = make_float4(m[0], m[1], m[2], m[3]);
        float4 mB = make_float4(m[4], m[5], m[6], m[7]);
        float4* o4 = (float4*)out;
        int tb0 = batch << 10;
        #pragma unroll
        for (int t = tid; t < 1024; t += 256) {
            o4[(size_t)(tb0 + t) * 2]     = mA;
            o4[(size_t)(tb0 + t) * 2 + 1] = mB;
        }
        if (tid == 0) {
            out[524288 + batch * 2]     = (float)i1;
            out[524288 + batch * 2 + 1] = (float)i2;
            asm volatile("s_waitcnt vmcnt(0)" ::: "memory");
            int p2 = atomicAdd(&wsi[GDOFF], 1);
            *sfp = (p2 == 63) ? 2 : 0;
        }
        __syncthreads();
        if (*sfp == 2) {                  // last batch-finisher: loss
            if (tid < 8) cnt8[tid] = 0;
            __syncthreads();
            if (tid < 64) {
                float vv[8];
                #pragma unroll
                for (int c = 0; c < 8; ++c)
                    vv[c] = atomicAdd(&ws[SCOFF + tid * 8 + c], 0.0f);
                int j1, j2;
                top2_of8(vv, j1, j2);
                atomicAdd(&cnt8[j1], 1);
                atomicAdd(&cnt8[j2], 1);
            }
            __syncthreads();
            if (tid == 0) {
                float kl = 0.0f;
                #pragma unroll
                for (int c = 0; c < 8; ++c) {
                    float usage = (float)cnt8[c] / 64.0f;
                    kl += 0.125f * (logf(0.125f) - logf(usage));
                }
                kl *= 0.125f;             // / E (batchmean)
                float auxv = atomicAdd(&ws[AUXOFF], 0.0f);
                out[524416] = 1e-3f * kl + 1e-3f * (auxv / 524288.0f);
            }
        }
    }
}

extern "C" void kernel_launch(void* const* d_in, const int* in_sizes, int n_in,
                              void* d_out, int out_size, void* d_ws, size_t ws_size,
                              hipStream_t stream) {
    const float* x   = (const float*)d_in[0];
    const float* Wq  = (const float*)d_in[1];
    const float* bq  = (const float*)d_in[2];
    const float* key = (const float*)d_in[3];
    float* out = (float*)d_out;
    float* ws  = (float*)d_ws;

    k01_prep<<<128,  256, 0, stream>>>(Wq, key, bq, ws);
    k2_main <<<1024, 256, 0, stream>>>(x, ws, out);
}

// Round 4
// 476.493 us; speedup vs baseline: 1.0041x; 1.0041x over previous
//
#include <hip/hip_runtime.h>
#include <math.h>

// Workspace layout (4-byte words):
#define W2OFF  0        // 8192 floats: W2[e][d] = sum_o key[e][o]*Wq[o][d]
#define B2OFF  8192     // 8 floats:    b2[e]    = sum_d bq[d]*key[e][d]
#define SCOFF  8200     // 512 floats:  score sums [batch][e]
#define AUXOFF 8712     // 1 float:     sum of w*log(w+1e-9)
#define CNTOFF 8713     // 64 ints:     per-batch block-arrival counters
#define GDOFF  8777     // 1 int:       batch-finisher arrival counter
#define ZTOT   578      // words to zero starting at SCOFF (512+1+64+1)
#define KEYP   1088     // skew-padded per-expert LDS stride for key

// ---------------- k01: W2 = key@Wq, b2 = bq.key, zero accumulators ----------------
__global__ __launch_bounds__(256) void k01_prep(const float* __restrict__ Wq,
                                                const float* __restrict__ key,
                                                const float* __restrict__ bq,
                                                float* __restrict__ ws) {
    __shared__ __attribute__((aligned(16))) float keyl[8 * KEYP];  // 34 KB
    __shared__ float part[256 * 8];                                // 8 KB
    __shared__ float part2[64];
    int tid = threadIdx.x;
    int blk = blockIdx.x;

    // distributed zeroing: 128 blocks x 5 words covers 578
    if (tid < 5) {
        int i = blk * 5 + tid;
        if (i < ZTOT) ws[SCOFF + i] = 0.0f;
    }

    // stage key with skew (scalar stores; global reads stay coalesced)
    #pragma unroll
    for (int k = 0; k < 32; ++k) {
        int idx = tid + 256 * k;         // 0..8191
        int e = idx >> 10, o = idx & 1023;
        keyl[e * KEYP + o + (o >> 5)] = key[idx];
    }
    __syncthreads();

    int dl = tid & 7;
    int og = tid >> 3;                   // 0..31
    int d  = blk * 8 + dl;
    int kob = og * 33;                   // og*32 + skew(og)
    float acc[8];
    #pragma unroll
    for (int e = 0; e < 8; ++e) acc[e] = 0.0f;
    #pragma unroll
    for (int oo = 0; oo < 32; ++oo) {    // full unroll: 32 Wq loads in flight
        int o = og * 32 + oo;
        float wv = Wq[o * 1024 + d];
        #pragma unroll
        for (int e = 0; e < 8; ++e) acc[e] += keyl[e * KEYP + kob + oo] * wv;
    }
    #pragma unroll
    for (int e = 0; e < 8; ++e) part[tid * 8 + e] = acc[e];
    __syncthreads();
    if (tid < 64) {
        int d2 = tid >> 3, e = tid & 7;
        float s = 0.0f;
        #pragma unroll
        for (int g = 0; g < 32; ++g) s += part[(g * 8 + d2) * 8 + e];
        ws[W2OFF + e * 1024 + blk * 8 + d2] = s;
    }

    // block 0 additionally computes b2 using the LDS-staged key (tree reduce)
    if (blk == 0) {
        __syncthreads();
        float p[8];
        #pragma unroll
        for (int e = 0; e < 8; ++e) p[e] = 0.0f;
        #pragma unroll
        for (int k = 0; k < 4; ++k) {
            int d2 = tid + 256 * k;
            float bv = bq[d2];
            int kd = d2 + (d2 >> 5);
            #pragma unroll
            for (int e = 0; e < 8; ++e) p[e] += bv * keyl[e * KEYP + kd];
        }
        #pragma unroll
        for (int e = 0; e < 8; ++e) part[tid * 8 + e] = p[e];
        __syncthreads();
        if (tid < 64) {
            int e = tid & 7, g = tid >> 3;
            float s = 0.0f;
            #pragma unroll
            for (int k = 0; k < 32; ++k) s += part[(g * 32 + k) * 8 + e];
            part2[g * 8 + e] = s;
        }
        __syncthreads();
        if (tid < 8) {
            float s = 0.0f;
            #pragma unroll
            for (int g = 0; g < 8; ++g) s += part2[g * 8 + tid];
            ws[B2OFF + tid] = s;
        }
    }
}

__device__ __forceinline__ void top2_of8(const float* v, int& i1, int& i2) {
    i1 = 0; float b1 = v[0];
    #pragma unroll
    for (int e = 1; e < 8; ++e) if (v[e] > b1) { b1 = v[e]; i1 = e; }
    i2 = -1; float b2 = -3.4e38f;
    #pragma unroll
    for (int e = 0; e < 8; ++e) if (e != i1 && v[e] > b2) { b2 = v[e]; i2 = e; }
}

// ---------------- k2: stream x -> scores -> INLINE softmax -> fused finisher ----------------
// 1024 blocks x 256 thr; block = 64 consecutive tokens of one batch.
// LDS = 32KB (W2) + 8KB (transpose/finisher scratch) = 40960 B -> 4 blocks/CU.
// amdgpu_waves_per_eu(4,4): pins the VGPR cap at 512/4 = 128. R3 lesson:
// __launch_bounds__(256,4) sets only a MINIMUM waves/EU; the compiler then
// targeted 8 waves/EU, capped VGPRs at 64, and spilled acc[4][8] to scratch
// (WRITE_SIZE 2.6MB -> 236MB, k2 50us -> 210us). The (4,4) max side forbids
// that occupancy-chasing.
// Cross-block comms are atomics-only (NO threadfence: r1 showed the XCD-L2
// invalidate costs 5x).
__global__ __launch_bounds__(256)
__attribute__((amdgpu_waves_per_eu(4, 4)))
void k2_main(const float* __restrict__ x,
             float* __restrict__ ws,
             float* __restrict__ out) {
    __shared__ __attribute__((aligned(16))) float w2l[8 * 1024];    // 32 KB
    __shared__ __attribute__((aligned(16))) float part[4 * 64 * 8]; // 8 KB per-wave [8][64]

    int tid  = threadIdx.x;
    int blk  = blockIdx.x;
    int lane = tid & 63;
    int w    = tid >> 6;
    int batch = blk >> 4;
    int tb    = blk * 64;
    int e = lane >> 3;      // expert owned after transpose
    int r = lane & 7;       // reduction slice -> cheap shfl masks 1/2/4

    float4* wl4 = (float4*)w2l;
    const float4* wg4 = (const float4*)(ws + W2OFF);
    #pragma unroll
    for (int k = 0; k < 8; ++k) wl4[tid + 256 * k] = wg4[tid + 256 * k];

    float b2e = ws[B2OFF + e];           // per-lane bias for owned expert
    const float scale = 0.03125f;        // 1024^-0.5
    float ssum = 0.0f;                   // score-sum accumulator (expert e, this wave's tokens)
    float aux  = 0.0f;                   // aux accumulator (expert e, this wave's tokens)
    __syncthreads();

    const float4* x4 = (const float4*)x;
    float* pw = part + w * 512;

    for (int p = 0; p < 4; ++p) {
        int t0 = tb + w * 16 + p * 4;
        float acc[4][8];
        #pragma unroll
        for (int j = 0; j < 4; ++j)
            #pragma unroll
            for (int c = 0; c < 8; ++c) acc[j][c] = 0.0f;

        #pragma unroll
        for (int i = 0; i < 4; ++i) {
            float4 xr[4];
            #pragma unroll
            for (int j = 0; j < 4; ++j)
                xr[j] = x4[(size_t)(t0 + j) * 256 + i * 64 + lane];
            #pragma unroll
            for (int c = 0; c < 8; ++c) {
                float4 w4 = wl4[c * 256 + i * 64 + lane];
                #pragma unroll
                for (int j = 0; j < 4; ++j)
                    acc[j][c] += w4.x * xr[j].x + w4.y * xr[j].y +
                                 w4.z * xr[j].z + w4.w * xr[j].w;
            }
        }

        #pragma unroll
        for (int j = 0; j < 4; ++j) {
            // swizzled wave-internal transpose: <=2-way bank alias on write & read
            #pragma unroll
            for (int c = 0; c < 8; ++c)
                pw[c * 64 + (lane ^ (c << 3))] = acc[j][c];
            float s = 0.0f;
            #pragma unroll
            for (int m = 0; m < 8; ++m)
                s += pw[e * 64 + ((r + 8 * m) ^ (e << 3))];
            s += __shfl_xor(s, 1);
            s += __shfl_xor(s, 2);
            s += __shfl_xor(s, 4);
            // s = full raw dot (token t0+j, expert e), replicated over r.
            float sc = (s + b2e) * scale;
            float mx = sc;
            mx = fmaxf(mx, __shfl_xor(mx, 8));
            mx = fmaxf(mx, __shfl_xor(mx, 16));
            mx = fmaxf(mx, __shfl_xor(mx, 32));
            float wv = expf(sc - mx);
            float sm = wv;
            sm += __shfl_xor(sm, 8);
            sm += __shfl_xor(sm, 16);
            sm += __shfl_xor(sm, 32);
            float wgt = wv / sm;
            ssum += wgt;
            aux  += wgt * logf(wgt + 1e-9f);
        }
    }

    // cross-expert reduce of aux (lane value covers expert e only; replicated over r)
    aux += __shfl_xor(aux, 8);
    aux += __shfl_xor(aux, 16);
    aux += __shfl_xor(aux, 32);

    __syncthreads();                      // transpose buffer free; reuse for block reduce
    if (r == 0) part[w * 8 + e] = ssum;   // 32 floats
    if (lane == 0) part[32 + w] = aux;    // 4 floats
    __syncthreads();
    if (tid < 8) {
        float s2 = part[tid] + part[8 + tid] + part[16 + tid] + part[24 + tid];
        atomicAdd(&ws[SCOFF + batch * 8 + tid], s2);
    }
    if (tid == 0) {
        float a = part[32] + part[33] + part[34] + part[35];
        atomicAdd(&ws[AUXOFF], a);
    }

    // ---- fused finisher; atomics-only, NO threadfence ----
    int* wsi = (int*)ws;
    float* sc8  = part + 40;              // aliases into part (free now)
    int*   cnt8 = (int*)(part + 48);
    int*   sfp  = (int*)(part + 56);
    __syncthreads();   // compiler emits s_waitcnt vmcnt(0): score/aux atomics complete
    if (tid == 0) {
        asm volatile("s_waitcnt vmcnt(0)" ::: "memory");
        int prev = atomicAdd(&wsi[CNTOFF + batch], 1);
        *sfp = (prev == 15) ? 1 : 0;
    }
    __syncthreads();
    if (*sfp) {
        // coherent read of this batch's final score sums via atomic RMW
        if (tid < 8) sc8[tid] = atomicAdd(&ws[SCOFF + batch * 8 + tid], 0.0f);
        __syncthreads();
        float v[8];
        #pragma unroll
        for (int c = 0; c < 8; ++c) v[c] = sc8[c];
        int i1, i2;
        top2_of8(v, i1, i2);
        float m[8];
        #pragma unroll
        for (int c = 0; c < 8; ++c) m[c] = (c == i1 || c == i2) ? 1.0f : 0.0f;
        float4 mA = make_float4(m[0], m[1], m[2], m[3]);
        float4 mB = make_float4(m[4], m[5], m[6], m[7]);
        float4* o4 = (float4*)out;
        int tb0 = batch << 10;
        #pragma unroll
        for (int t = tid; t < 1024; t += 256) {
            o4[(size_t)(tb0 + t) * 2]     = mA;
            o4[(size_t)(tb0 + t) * 2 + 1] = mB;
        }
        if (tid == 0) {
            out[524288 + batch * 2]     = (float)i1;
            out[524288 + batch * 2 + 1] = (float)i2;
            asm volatile("s_waitcnt vmcnt(0)" ::: "memory");
            int p2 = atomicAdd(&wsi[GDOFF], 1);
            *sfp = (p2 == 63) ? 2 : 0;
        }
        __syncthreads();
        if (*sfp == 2) {                  // last batch-finisher: loss
            if (tid < 8) cnt8[tid] = 0;
            __syncthreads();
            if (tid < 64) {
                float vv[8];
                #pragma unroll
                for (int c = 0; c < 8; ++c)
                    vv[c] = atomicAdd(&ws[SCOFF + tid * 8 + c], 0.0f);
                int j1, j2;
                top2_of8(vv, j1, j2);
                atomicAdd(&cnt8[j1], 1);
                atomicAdd(&cnt8[j2], 1);
            }
            __syncthreads();
            if (tid == 0) {
                float kl = 0.0f;
                #pragma unroll
                for (int c = 0; c < 8; ++c) {
                    float usage = (float)cnt8[c] / 64.0f;
                    kl += 0.125f * (logf(0.125f) - logf(usage));
                }
                kl *= 0.125f;             // / E (batchmean)
                float auxv = atomicAdd(&ws[AUXOFF], 0.0f);
                out[524416] = 1e-3f * kl + 1e-3f * (auxv / 524288.0f);
            }
        }
    }
}

extern "C" void kernel_launch(void* const* d_in, const int* in_sizes, int n_in,
                              void* d_out, int out_size, void* d_ws, size_t ws_size,
                              hipStream_t stream) {
    const float* x   = (const float*)d_in[0];
    const float* Wq  = (const float*)d_in[1];
    const float* bq  = (const float*)d_in[2];
    const float* key = (const float*)d_in[3];
    float* out = (float*)d_out;
    float* ws  = (float*)d_ws;

    k01_prep<<<128,  256, 0, stream>>>(Wq, key, bq, ws);
    k2_main <<<1024, 256, 0, stream>>>(x, ws, out);
}

// Round 6
// 382.913 us; speedup vs baseline: 1.2495x; 1.2444x over previous
//
#include <hip/hip_runtime.h>
#include <math.h>

// Workspace layout (4-byte words):
#define W2OFF  0        // 8192 floats: W2[e][d] = sum_o key[e][o]*Wq[o][d]
#define B2OFF  8192     // 8 floats:    b2[e]    = sum_d bq[d]*key[e][d]
#define SCOFF  8200     // 512 floats:  score sums [batch][e]
#define AUXOFF 8712     // 1 float:     sum of w*log(w+1e-9)
#define CNTOFF 8713     // 64 ints:     per-batch block-arrival counters
#define GDOFF  8777     // 1 int:       batch-finisher arrival counter
#define ZTOT   578      // words to zero starting at SCOFF (512+1+64+1)
#define KEYP   1088     // skew-padded per-expert LDS stride for key

// ---------------- k01: W2 = key@Wq, b2 = bq.key, zero accumulators ----------------
__global__ __launch_bounds__(256) void k01_prep(const float* __restrict__ Wq,
                                                const float* __restrict__ key,
                                                const float* __restrict__ bq,
                                                float* __restrict__ ws) {
    __shared__ __attribute__((aligned(16))) float keyl[8 * KEYP];  // 34 KB
    __shared__ float part[256 * 8];                                // 8 KB
    __shared__ float part2[64];
    int tid = threadIdx.x;
    int blk = blockIdx.x;

    // distributed zeroing: 128 blocks x 5 words covers 578
    if (tid < 5) {
        int i = blk * 5 + tid;
        if (i < ZTOT) ws[SCOFF + i] = 0.0f;
    }

    // stage key with skew (scalar stores; global reads stay coalesced)
    #pragma unroll
    for (int k = 0; k < 32; ++k) {
        int idx = tid + 256 * k;         // 0..8191
        int e = idx >> 10, o = idx & 1023;
        keyl[e * KEYP + o + (o >> 5)] = key[idx];
    }
    __syncthreads();

    int dl = tid & 7;
    int og = tid >> 3;                   // 0..31
    int d  = blk * 8 + dl;
    int kob = og * 33;                   // og*32 + skew(og)
    float acc[8];
    #pragma unroll
    for (int e = 0; e < 8; ++e) acc[e] = 0.0f;
    #pragma unroll
    for (int oo = 0; oo < 32; ++oo) {    // full unroll: 32 Wq loads in flight
        int o = og * 32 + oo;
        float wv = Wq[o * 1024 + d];
        #pragma unroll
        for (int e = 0; e < 8; ++e) acc[e] += keyl[e * KEYP + kob + oo] * wv;
    }
    #pragma unroll
    for (int e = 0; e < 8; ++e) part[tid * 8 + e] = acc[e];
    __syncthreads();
    if (tid < 64) {
        int d2 = tid >> 3, e = tid & 7;
        float s = 0.0f;
        #pragma unroll
        for (int g = 0; g < 32; ++g) s += part[(g * 8 + d2) * 8 + e];
        ws[W2OFF + e * 1024 + blk * 8 + d2] = s;
    }

    // block 0 additionally computes b2 using the LDS-staged key (tree reduce)
    if (blk == 0) {
        __syncthreads();
        float p[8];
        #pragma unroll
        for (int e = 0; e < 8; ++e) p[e] = 0.0f;
        #pragma unroll
        for (int k = 0; k < 4; ++k) {
            int d2 = tid + 256 * k;
            float bv = bq[d2];
            int kd = d2 + (d2 >> 5);
            #pragma unroll
            for (int e = 0; e < 8; ++e) p[e] += bv * keyl[e * KEYP + kd];
        }
        #pragma unroll
        for (int e = 0; e < 8; ++e) part[tid * 8 + e] = p[e];
        __syncthreads();
        if (tid < 64) {
            int e = tid & 7, g = tid >> 3;
            float s = 0.0f;
            #pragma unroll
            for (int k = 0; k < 32; ++k) s += part[(g * 32 + k) * 8 + e];
            part2[g * 8 + e] = s;
        }
        __syncthreads();
        if (tid < 8) {
            float s = 0.0f;
            #pragma unroll
            for (int g = 0; g < 8; ++g) s += part2[g * 8 + tid];
            ws[B2OFF + tid] = s;
        }
    }
}

__device__ __forceinline__ void top2_of8(const float* v, int& i1, int& i2) {
    i1 = 0; float b1 = v[0];
    #pragma unroll
    for (int e = 1; e < 8; ++e) if (v[e] > b1) { b1 = v[e]; i1 = e; }
    i2 = -1; float b2 = -3.4e38f;
    #pragma unroll
    for (int e = 0; e < 8; ++e) if (e != i1 && v[e] > b2) { b2 = v[e]; i2 = e; }
}

// ---------------- k2: stream x -> scores -> INLINE softmax -> fused finisher ----------------
// 1024 blocks x 256 thr; block = 64 consecutive tokens of one batch.
// LDS = 32KB (W2) + 8KB (transpose/finisher scratch) = 40960 B -> 4 blocks/CU.
// REGISTER BUDGET (R3/R4 lesson): at LDS=40960 the compiler caps VGPRs at 64
// regardless of launch-bounds/waves_per_eu attributes (both tried, no effect).
// j=4 token blocking (acc[4][8]+xr[4] ~ 70 live regs) spilled 236MB to
// scratch at that cap. Fix: j=2 blocking (acc[2][8]+xr[2] ~ 55 live) fits 64.
// p-loop pinned unroll 1 so the compiler can't recreate j=4 pressure.
// Cost: w2l LDS reads x2 (hidden: ~15% of LDS BW under the 42us HBM stream).
// Cross-block comms are atomics-only (NO threadfence: r1 showed the XCD-L2
// invalidate costs 5x).
__global__ __launch_bounds__(256) void k2_main(const float* __restrict__ x,
                                               float* __restrict__ ws,
                                               float* __restrict__ out) {
    __shared__ __attribute__((aligned(16))) float w2l[8 * 1024];    // 32 KB
    __shared__ __attribute__((aligned(16))) float part[4 * 64 * 8]; // 8 KB per-wave [8][64]

    int tid  = threadIdx.x;
    int blk  = blockIdx.x;
    int lane = tid & 63;
    int w    = tid >> 6;
    int batch = blk >> 4;
    int tb    = blk * 64;
    int e = lane >> 3;      // expert owned after transpose
    int r = lane & 7;       // reduction slice -> cheap shfl masks 1/2/4

    float4* wl4 = (float4*)w2l;
    const float4* wg4 = (const float4*)(ws + W2OFF);
    #pragma unroll
    for (int k = 0; k < 8; ++k) wl4[tid + 256 * k] = wg4[tid + 256 * k];

    float b2e = ws[B2OFF + e];           // per-lane bias for owned expert
    const float scale = 0.03125f;        // 1024^-0.5
    float ssum = 0.0f;                   // score-sum accumulator (expert e, this wave's tokens)
    float aux  = 0.0f;                   // aux accumulator (expert e, this wave's tokens)
    __syncthreads();

    const float4* x4 = (const float4*)x;
    float* pw = part + w * 512;

    #pragma unroll 1
    for (int p = 0; p < 8; ++p) {
        int t0 = tb + w * 16 + p * 2;
        float acc[2][8];
        #pragma unroll
        for (int j = 0; j < 2; ++j)
            #pragma unroll
            for (int c = 0; c < 8; ++c) acc[j][c] = 0.0f;

        #pragma unroll
        for (int i = 0; i < 4; ++i) {
            float4 xr0 = x4[(size_t)t0 * 256 + i * 64 + lane];
            float4 xr1 = x4[(size_t)(t0 + 1) * 256 + i * 64 + lane];
            #pragma unroll
            for (int c = 0; c < 8; ++c) {
                float4 w4 = wl4[c * 256 + i * 64 + lane];
                acc[0][c] += w4.x * xr0.x + w4.y * xr0.y + w4.z * xr0.z + w4.w * xr0.w;
                acc[1][c] += w4.x * xr1.x + w4.y * xr1.y + w4.z * xr1.z + w4.w * xr1.w;
            }
        }

        #pragma unroll
        for (int j = 0; j < 2; ++j) {
            // swizzled wave-internal transpose: <=2-way bank alias on write & read
            #pragma unroll
            for (int c = 0; c < 8; ++c)
                pw[c * 64 + (lane ^ (c << 3))] = acc[j][c];
            float s = 0.0f;
            #pragma unroll
            for (int m = 0; m < 8; ++m)
                s += pw[e * 64 + ((r + 8 * m) ^ (e << 3))];
            s += __shfl_xor(s, 1);
            s += __shfl_xor(s, 2);
            s += __shfl_xor(s, 4);
            // s = full raw dot (token t0+j, expert e), replicated over r.
            float sc = (s + b2e) * scale;
            float mx = sc;
            mx = fmaxf(mx, __shfl_xor(mx, 8));
            mx = fmaxf(mx, __shfl_xor(mx, 16));
            mx = fmaxf(mx, __shfl_xor(mx, 32));
            float wv = expf(sc - mx);
            float sm = wv;
            sm += __shfl_xor(sm, 8);
            sm += __shfl_xor(sm, 16);
            sm += __shfl_xor(sm, 32);
            float wgt = wv / sm;
            ssum += wgt;
            aux  += wgt * logf(wgt + 1e-9f);
        }
    }

    // cross-expert reduce of aux (lane value covers expert e only; replicated over r)
    aux += __shfl_xor(aux, 8);
    aux += __shfl_xor(aux, 16);
    aux += __shfl_xor(aux, 32);

    __syncthreads();                      // transpose buffer free; reuse for block reduce
    if (r == 0) part[w * 8 + e] = ssum;   // 32 floats
    if (lane == 0) part[32 + w] = aux;    // 4 floats
    __syncthreads();
    if (tid < 8) {
        float s2 = part[tid] + part[8 + tid] + part[16 + tid] + part[24 + tid];
        atomicAdd(&ws[SCOFF + batch * 8 + tid], s2);
    }
    if (tid == 0) {
        float a = part[32] + part[33] + part[34] + part[35];
        atomicAdd(&ws[AUXOFF], a);
    }

    // ---- fused finisher; atomics-only, NO threadfence ----
    int* wsi = (int*)ws;
    float* sc8  = part + 40;              // aliases into part (free now)
    int*   cnt8 = (int*)(part + 48);
    int*   sfp  = (int*)(part + 56);
    __syncthreads();   // compiler emits s_waitcnt vmcnt(0): score/aux atomics complete
    if (tid == 0) {
        asm volatile("s_waitcnt vmcnt(0)" ::: "memory");
        int prev = atomicAdd(&wsi[CNTOFF + batch], 1);
        *sfp = (prev == 15) ? 1 : 0;
    }
    __syncthreads();
    if (*sfp) {
        // coherent read of this batch's final score sums via atomic RMW
        if (tid < 8) sc8[tid] = atomicAdd(&ws[SCOFF + batch * 8 + tid], 0.0f);
        __syncthreads();
        float v[8];
        #pragma unroll
        for (int c = 0; c < 8; ++c) v[c] = sc8[c];
        int i1, i2;
        top2_of8(v, i1, i2);
        float m[8];
        #pragma unroll
        for (int c = 0; c < 8; ++c) m[c] = (c == i1 || c == i2) ? 1.0f : 0.0f;
        float4 mA = make_float4(m[0], m[1], m[2], m[3]);
        float4 mB = make_float4(m[4], m[5], m[6], m[7]);
        float4* o4 = (float4*)out;
        int tb0 = batch << 10;
        #pragma unroll
        for (int t = tid; t < 1024; t += 256) {
            o4[(size_t)(tb0 + t) * 2]     = mA;
            o4[(size_t)(tb0 + t) * 2 + 1] = mB;
        }
        if (tid == 0) {
            out[524288 + batch * 2]     = (float)i1;
            out[524288 + batch * 2 + 1] = (float)i2;
            asm volatile("s_waitcnt vmcnt(0)" ::: "memory");
            int p2 = atomicAdd(&wsi[GDOFF], 1);
            *sfp = (p2 == 63) ? 2 : 0;
        }
        __syncthreads();
        if (*sfp == 2) {                  // last batch-finisher: loss
            if (tid < 8) cnt8[tid] = 0;
            __syncthreads();
            if (tid < 64) {
                float vv[8];
                #pragma unroll
                for (int c = 0; c < 8; ++c)
                    vv[c] = atomicAdd(&ws[SCOFF + tid * 8 + c], 0.0f);
                int j1, j2;
                top2_of8(vv, j1, j2);
                atomicAdd(&cnt8[j1], 1);
                atomicAdd(&cnt8[j2], 1);
            }
            __syncthreads();
            if (tid == 0) {
                float kl = 0.0f;
                #pragma unroll
                for (int c = 0; c < 8; ++c) {
                    float usage = (float)cnt8[c] / 64.0f;
                    kl += 0.125f * (logf(0.125f) - logf(usage));
                }
                kl *= 0.125f;             // / E (batchmean)
                float auxv = atomicAdd(&ws[AUXOFF], 0.0f);
                out[524416] = 1e-3f * kl + 1e-3f * (auxv / 524288.0f);
            }
        }
    }
}

extern "C" void kernel_launch(void* const* d_in, const int* in_sizes, int n_in,
                              void* d_out, int out_size, void* d_ws, size_t ws_size,
                              hipStream_t stream) {
    const float* x   = (const float*)d_in[0];
    const float* Wq  = (const float*)d_in[1];
    const float* bq  = (const float*)d_in[2];
    const float* key = (const float*)d_in[3];
    float* out = (float*)d_out;
    float* ws  = (float*)d_ws;

    k01_prep<<<128,  256, 0, stream>>>(Wq, key, bq, ws);
    k2_main <<<1024, 256, 0, stream>>>(x, ws, out);
}